// Round 1
// 169.680 us; speedup vs baseline: 1.3899x; 1.3899x over previous
//
#include <hip/hip_runtime.h>

// (B,C,L,H,W) = (4,64,16,32,32), K=1024, D=C=64
constexpr int Cc   = 64;
constexpr int Kc   = 1024;
constexpr int Dc   = 64;
constexpr int LHWc = 16 * 32 * 32;        // 16384
constexpr int Nc   = 4 * LHWc;            // 65536 vectors
constexpr int QSIZE    = 4 * Cc * LHWc;   // 4194304
constexpr int OFF_LOSS = QSIZE;           // 4194304
constexpr int OFF_IDX  = QSIZE + 1;       // 4194305

constexpr int BLK_ROWS = 256;             // rows (vectors) per block
constexpr int MBW      = 32;              // rows per wave (2 MFMA row-tiles)
constexpr int XPAD     = 68;              // LDS row stride (16B-aligned, bank-spread)

typedef __attribute__((ext_vector_type(8))) short short8;   // 8 x bf16 bits
typedef __attribute__((ext_vector_type(4))) float f32x4;

static __device__ __forceinline__ unsigned short f2bf(float f) {
    unsigned u = __float_as_uint(f);
    u += 0x7FFFu + ((u >> 16) & 1u);      // RNE (finite data only)
    return (unsigned short)(u >> 16);
}
static __device__ __forceinline__ float bf2f(unsigned short h) {
    return __uint_as_float(((unsigned)h) << 16);
}

// Prep: zero loss; split codebook into bf16 hi/lo; exact-chain c2 (same fma
// order as the reference-matching kernel).
__global__ void vq_prep(const float* __restrict__ cb, float* __restrict__ out,
                        unsigned short* __restrict__ cbh,
                        unsigned short* __restrict__ cbl,
                        float* __restrict__ c2)
{
    const int k = blockIdx.x * 256 + threadIdx.x;
    if (k == 0) out[OFF_LOSS] = 0.0f;
    if (k >= Kc) return;
    const float* c = cb + (size_t)k * Dc;
    float s = 0.f;
#pragma unroll
    for (int d = 0; d < Dc; ++d) {
        float v = c[d];
        s = __builtin_fmaf(v, v, s);
        unsigned short h = f2bf(v);
        cbh[(size_t)k * Dc + d] = h;
        cbl[(size_t)k * Dc + d] = f2bf(v - bf2f(h));
    }
    c2[k] = s;
}

__global__ __launch_bounds__(512, 2) void vq_main(
    const float* __restrict__ in, const float* __restrict__ codebook,
    const unsigned short* __restrict__ cbh,
    const unsigned short* __restrict__ cbl,
    const float* __restrict__ c2g, float* __restrict__ out)
{
    __shared__ float xs[BLK_ROWS][XPAD];
    __shared__ float xs2[BLK_ROWS];
    __shared__ int   cand[BLK_ROWS];

    const int tid  = threadIdx.x;
    const int lane = tid & 63;
    const int w    = __builtin_amdgcn_readfirstlane(tid >> 6);
    const int col  = lane & 15;           // MFMA n / A-row lane index
    const int g    = lane >> 4;           // MFMA k-slot group

    const int bq = blockIdx.x >> 6;                    // batch index
    const int p0 = (blockIdx.x & 63) * BLK_ROWS;       // LHW offset
    const size_t inBase = (size_t)bq * (Cc * LHWc) + p0;

    // ---- stage X[256 rows][64 d] into LDS (coalesced global reads) ----
#pragma unroll
    for (int i = 0; i < 32; ++i) {
        int idx = i * 512 + tid;
        int d = idx >> 8, row = idx & 255;
        xs[row][d] = in[inBase + (size_t)d * LHWc + row];
    }
    __syncthreads();

    // ---- x2 per row: exact ascending fma chain (reference-identical) ----
    if (tid < BLK_ROWS) {
        float s = 0.f;
#pragma unroll
        for (int d = 0; d < Dc; ++d) s = __builtin_fmaf(xs[tid][d], xs[tid][d], s);
        xs2[tid] = s;
    }
    __syncthreads();

    const int wrow0 = w * MBW;

    // ---- build A fragments (bf16 hi/lo split), live across whole k-loop ----
    short8 xh[2][2], xl[2][2];   // [row-tile][kt]
#pragma unroll
    for (int t = 0; t < 2; ++t) {
#pragma unroll
        for (int kt = 0; kt < 2; ++kt) {
            const float* px = &xs[wrow0 + t * 16 + col][kt * 32 + g * 8];
            f32x4 v0 = *(const f32x4*)px;
            f32x4 v1 = *(const f32x4*)(px + 4);
            short8 h8, l8;
#pragma unroll
            for (int j = 0; j < 4; ++j) {
                unsigned short ha = f2bf(v0[j]);
                h8[j]     = (short)ha;
                l8[j]     = (short)f2bf(v0[j] - bf2f(ha));
                unsigned short hb = f2bf(v1[j]);
                h8[4 + j] = (short)hb;
                l8[4 + j] = (short)f2bf(v1[j] - bf2f(hb));
            }
            xh[t][kt] = h8; xl[t][kt] = l8;
        }
    }

    float x2r[2][4];
#pragma unroll
    for (int t = 0; t < 2; ++t)
#pragma unroll
        for (int r = 0; r < 4; ++r)
            x2r[t][r] = xs2[wrow0 + t * 16 + g * 4 + r];

    // ---- streaming top-2 state per (tile, reg) slot ----
    float bV[2][4], sV[2][4];
    int   bK[2][4], sK[2][4];
#pragma unroll
    for (int t = 0; t < 2; ++t)
#pragma unroll
        for (int r = 0; r < 4; ++r) {
            bV[t][r] = 3.4e38f; sV[t][r] = 3.4e38f; bK[t][r] = 0; sK[t][r] = 0;
        }

    const unsigned short* bhp = cbh + (size_t)col * Dc + g * 8;
    const unsigned short* blp = cbl + (size_t)col * Dc + g * 8;

    short8 bh0 = *(const short8*)(bhp);
    short8 bh1 = *(const short8*)(bhp + 32);
    short8 bl0 = *(const short8*)(blp);
    short8 bl1 = *(const short8*)(blp + 32);

#pragma unroll 1
    for (int ct = 0; ct < 64; ++ct) {
        short8 ch0 = bh0, ch1 = bh1, cl0 = bl0, cl1 = bl1;
        bhp += 16 * Dc; blp += 16 * Dc;
        if (ct < 63) {                    // 1-deep register prefetch
            bh0 = *(const short8*)(bhp);
            bh1 = *(const short8*)(bhp + 32);
            bl0 = *(const short8*)(blp);
            bl1 = *(const short8*)(blp + 32);
        }

        f32x4 acc0 = {0.f, 0.f, 0.f, 0.f};
        f32x4 acc1 = {0.f, 0.f, 0.f, 0.f};
        // 3-pass split: hh + hl + lh (ll term ~1e-8, covered by exact recheck)
        acc0 = __builtin_amdgcn_mfma_f32_16x16x32_bf16(xh[0][0], ch0, acc0, 0, 0, 0);
        acc0 = __builtin_amdgcn_mfma_f32_16x16x32_bf16(xh[0][1], ch1, acc0, 0, 0, 0);
        acc0 = __builtin_amdgcn_mfma_f32_16x16x32_bf16(xh[0][0], cl0, acc0, 0, 0, 0);
        acc0 = __builtin_amdgcn_mfma_f32_16x16x32_bf16(xh[0][1], cl1, acc0, 0, 0, 0);
        acc0 = __builtin_amdgcn_mfma_f32_16x16x32_bf16(xl[0][0], ch0, acc0, 0, 0, 0);
        acc0 = __builtin_amdgcn_mfma_f32_16x16x32_bf16(xl[0][1], ch1, acc0, 0, 0, 0);

        acc1 = __builtin_amdgcn_mfma_f32_16x16x32_bf16(xh[1][0], ch0, acc1, 0, 0, 0);
        acc1 = __builtin_amdgcn_mfma_f32_16x16x32_bf16(xh[1][1], ch1, acc1, 0, 0, 0);
        acc1 = __builtin_amdgcn_mfma_f32_16x16x32_bf16(xh[1][0], cl0, acc1, 0, 0, 0);
        acc1 = __builtin_amdgcn_mfma_f32_16x16x32_bf16(xh[1][1], cl1, acc1, 0, 0, 0);
        acc1 = __builtin_amdgcn_mfma_f32_16x16x32_bf16(xl[1][0], ch0, acc1, 0, 0, 0);
        acc1 = __builtin_amdgcn_mfma_f32_16x16x32_bf16(xl[1][1], ch1, acc1, 0, 0, 0);

        const int   kcol = ct * 16 + col;
        const float c2v  = c2g[kcol];
#pragma unroll
        for (int t = 0; t < 2; ++t) {
#pragma unroll
            for (int r = 0; r < 4; ++r) {
                float a  = (t == 0) ? acc0[r] : acc1[r];
                float d2 = __builtin_fmaf(-2.f, a, x2r[t][r]) + c2v;
                bool  c1 = d2 < bV[t][r];
                float mx  = c1 ? bV[t][r] : d2;
                int   mxk = c1 ? bK[t][r] : kcol;
                bV[t][r] = c1 ? d2 : bV[t][r];
                bK[t][r] = c1 ? kcol : bK[t][r];
                bool  cc2 = mx < sV[t][r];
                sV[t][r] = cc2 ? mx : sV[t][r];
                sK[t][r] = cc2 ? mxk : sK[t][r];
            }
        }
    }

    // ---- butterfly top-2 merge across the 16 lanes sharing a row ----
#pragma unroll
    for (int m = 1; m < 16; m <<= 1) {
#pragma unroll
        for (int t = 0; t < 2; ++t) {
#pragma unroll
            for (int r = 0; r < 4; ++r) {
                float ob  = __shfl_xor(bV[t][r], m, 64);
                int   obk = __shfl_xor(bK[t][r], m, 64);
                float os  = __shfl_xor(sV[t][r], m, 64);
                int   osk = __shfl_xor(sK[t][r], m, 64);
                bool  c1 = ob < bV[t][r];
                float nb  = c1 ? ob : bV[t][r];
                int   nbk = c1 ? obk : bK[t][r];
                float mx  = c1 ? bV[t][r] : ob;
                int   mxk = c1 ? bK[t][r] : obk;
                bool  c3 = os < sV[t][r];
                float ms  = c3 ? os : sV[t][r];
                int   msk = c3 ? osk : sK[t][r];
                bool  c4 = mx < ms;
                sV[t][r] = c4 ? mx : ms;
                sK[t][r] = c4 ? mxk : msk;
                bV[t][r] = nb; bK[t][r] = nbk;
            }
        }
    }
    if (col == 0) {
#pragma unroll
        for (int t = 0; t < 2; ++t)
#pragma unroll
            for (int r = 0; r < 4; ++r)
                cand[wrow0 + t * 16 + g * 4 + r] = bK[t][r] | (sK[t][r] << 16);
    }
    __syncthreads();

    // ---- exact recheck of top-2 (bit-identical reference chain) ----
    int kw = 0;
    if (lane < 32) {
        const int row = wrow0 + lane;
        const int cd  = cand[row];
        const int bk  = cd & 0xFFFF;
        const int sk  = cd >> 16;
        const float* cb0 = codebook + (size_t)bk * Dc;
        const float* cb1 = codebook + (size_t)sk * Dc;
        float a0 = 0.f, a1 = 0.f;
#pragma unroll 8
        for (int d = 0; d < Dc; ++d) {
            float xv = xs[row][d];
            a0 = __builtin_fmaf(xv, cb0[d], a0);
            a1 = __builtin_fmaf(xv, cb1[d], a1);
        }
        const float x2v = xs2[row];
        float db  = __builtin_fmaf(-2.f, a0, x2v) + c2g[bk];
        float dsv = __builtin_fmaf(-2.f, a1, x2v) + c2g[sk];
        kw = bk;
        if (dsv < db || (dsv == db && sk < bk)) kw = sk;
        out[OFF_IDX + blockIdx.x * BLK_ROWS + row] = (float)kw;
    }

    // ---- quantized write + loss (all 64 lanes: 2 lanes per row) ----
    const int rowh = lane & 31;
    const int chh  = lane >> 5;
    const int kwv  = __shfl(kw, rowh, 64);
    const int row  = wrow0 + rowh;
    const float* cbw = codebook + (size_t)kwv * Dc + chh * 32;
    float* qout = out + inBase + row;
    float ls = 0.f;
#pragma unroll
    for (int cc = 0; cc < 32; ++cc) {
        int c = chh * 32 + cc;
        float q = cbw[cc];
        qout[(size_t)c * LHWc] = q;
        float e = q - xs[row][c];
        ls = __builtin_fmaf(e, e, ls);
    }
#pragma unroll
    for (int off = 32; off > 0; off >>= 1) ls += __shfl_down(ls, off, 64);
    if (lane == 0) atomicAdd(&out[OFF_LOSS], ls * (1.25f / (float)QSIZE));
}

extern "C" void kernel_launch(void* const* d_in, const int* in_sizes, int n_in,
                              void* d_out, int out_size, void* d_ws, size_t ws_size,
                              hipStream_t stream) {
    const float* in = (const float*)d_in[0];   // [4,64,16,32,32] f32
    const float* cb = (const float*)d_in[1];   // [1024,64] f32
    float* out = (float*)d_out;
    (void)in_sizes; (void)n_in; (void)out_size; (void)ws_size;

    unsigned short* cbh = (unsigned short*)d_ws;                 // 128 KB
    unsigned short* cbl = cbh + (size_t)Kc * Dc;                 // 128 KB
    float*          c2  = (float*)(cbl + (size_t)Kc * Dc);       // 4 KB

    vq_prep<<<dim3(Kc / 256), dim3(256), 0, stream>>>(cb, out, cbh, cbl, c2);
    vq_main<<<dim3(Nc / BLK_ROWS), dim3(512), 0, stream>>>(in, cb, cbh, cbl, c2, out);
}